// Round 1
// baseline (658.129 us; speedup 1.0000x reference)
//
#include <hip/hip_runtime.h>
#include <hip/hip_bf16.h>
#include <math.h>

// RandomProjectionQuantizer:
//   mel [32,80,4000] f32, proj [2,80,64] f32, codebooks [2,1024,64] f32
//   codes[c,b,t] = argmax_k ( (mel[b,:,t] @ proj[c]) . cbn[c,k,:] )
// where cbn rows are L2-normalized. Normalization of the projected vector is a
// positive scale constant over k -> dropped. Codebook normalization folded to
// per-k scalar invn[k] applied to the raw dot product.

#define B      32
#define NMELS  80
#define TSTEPS 4000
#define NCB    2
#define KCB    1024
#define DDIM   64
#define TPB    256

__global__ __launch_bounds__(TPB) void rpq_kernel(
    const float* __restrict__ mel,
    const float* __restrict__ proj,
    const float* __restrict__ cb,
    int* __restrict__ out)
{
    const int tile = blockIdx.x;
    const int b    = blockIdx.y;
    const int c    = blockIdx.z;
    const int t    = tile * TPB + threadIdx.x;
    const int tc   = (t < TSTEPS) ? t : (TSTEPS - 1);   // clamp for safe loads

    __shared__ float projS[NMELS * DDIM];   // 20 KB
    __shared__ float invn[KCB];             // 4 KB

    const float* cbc = cb + (size_t)c * KCB * DDIM;

    // ---- stage proj[c] into LDS (coalesced float4) ----
    {
        const float4* src = (const float4*)(proj + (size_t)c * NMELS * DDIM);
        float4* dst = (float4*)projS;
        const int n4 = NMELS * DDIM / 4;  // 1280
        for (int i = threadIdx.x; i < n4; i += TPB) dst[i] = src[i];
    }

    // ---- per-block recompute of codebook inverse norms (cheap: ~0.4%) ----
    for (int j = 0; j < KCB / TPB; ++j) {
        const int k = threadIdx.x + TPB * j;
        const float4* r = (const float4*)(cbc + (size_t)k * DDIM);
        float s = 0.f;
        #pragma unroll
        for (int i = 0; i < DDIM / 4; ++i) {
            float4 v = r[i];
            s += v.x * v.x + v.y * v.y + v.z * v.z + v.w * v.w;
        }
        invn[k] = 1.0f / fmaxf(sqrtf(s), 1e-12f);
    }

    __syncthreads();

    // ---- phase 1: P[d] = sum_n mel[b,n,t] * proj[c,n,d]  (P in VGPRs) ----
    float P[DDIM];
    #pragma unroll
    for (int d = 0; d < DDIM; ++d) P[d] = 0.f;

    const float* melp = mel + ((size_t)b * NMELS) * TSTEPS + tc;
    for (int n = 0; n < NMELS; ++n) {
        const float m = melp[(size_t)n * TSTEPS];      // coalesced across lanes
        const float4* ps = (const float4*)(projS + n * DDIM);  // LDS broadcast
        #pragma unroll
        for (int i = 0; i < DDIM / 4; ++i) {
            float4 v = ps[i];
            P[4*i+0] = fmaf(m, v.x, P[4*i+0]);
            P[4*i+1] = fmaf(m, v.y, P[4*i+1]);
            P[4*i+2] = fmaf(m, v.z, P[4*i+2]);
            P[4*i+3] = fmaf(m, v.w, P[4*i+3]);
        }
    }

    // ---- phase 2: argmax_k  (P . cb[k]) * invn[k] ----
    // cb row address is wave-uniform -> expect scalar (s_load) codebook reads.
    float best = -INFINITY;
    int   bidx = 0;
    #pragma unroll 2
    for (int k = 0; k < KCB; ++k) {
        const float4* row = (const float4*)(cbc + (size_t)k * DDIM);
        float a0 = 0.f, a1 = 0.f, a2 = 0.f, a3 = 0.f;
        #pragma unroll
        for (int i = 0; i < DDIM / 4; ++i) {
            float4 v = row[i];
            a0 = fmaf(P[4*i+0], v.x, a0);
            a1 = fmaf(P[4*i+1], v.y, a1);
            a2 = fmaf(P[4*i+2], v.z, a2);
            a3 = fmaf(P[4*i+3], v.w, a3);
        }
        const float s = ((a0 + a1) + (a2 + a3)) * invn[k];
        if (s > best) { best = s; bidx = k; }   // strict > : first-max tie-break (np.argmax)
    }

    if (t < TSTEPS) {
        out[((size_t)c * B + b) * TSTEPS + t] = bidx;
    }
}

extern "C" void kernel_launch(void* const* d_in, const int* in_sizes, int n_in,
                              void* d_out, int out_size, void* d_ws, size_t ws_size,
                              hipStream_t stream) {
    const float* mel  = (const float*)d_in[0];
    const float* proj = (const float*)d_in[1];
    const float* cb   = (const float*)d_in[2];
    int* out = (int*)d_out;

    dim3 grid((TSTEPS + TPB - 1) / TPB, B, NCB);  // (16, 32, 2)
    dim3 block(TPB);
    rpq_kernel<<<grid, block, 0, stream>>>(mel, proj, cb, out);
}

// Round 3
// 508.372 us; speedup vs baseline: 1.2946x; 1.2946x over previous
//
#include <hip/hip_runtime.h>
#include <hip/hip_bf16.h>
#include <math.h>

// RandomProjectionQuantizer:
//   mel [32,80,4000] f32, proj [2,80,64] f32, codebooks [2,1024,64] f32
//   codes[c,b,t] = argmax_k ( (mel[b,:,t] @ proj[c]) . cb[c,k,:]/||cb[c,k,:]|| )
// p-normalization dropped (positive scale, const over k); cb norm folded to invn[k].
//
// Structure: TT=2 time-blocking (P[2][64] in VGPRs, each cb float feeds 2 FMAs),
// codebook streamed through double-buffered LDS k-tiles (reg-staged prefetch)
// so the inner loop is ds_read_b128 broadcast + v_fmac only — no s_load chains.

#define B      32
#define NMELS  80
#define TSTEPS 4000
#define NCB    2
#define KCB    1024
#define DDIM   64
#define TPB    256
#define TT     2
#define KT     64              // k-rows per LDS tile (16 KB)
#define NKT    (KCB / KT)      // 16 tiles

__global__ __launch_bounds__(TPB, 2) void rpq_kernel(
    const float* __restrict__ mel,
    const float* __restrict__ proj,
    const float* __restrict__ cb,
    int* __restrict__ out)
{
    const int tid = threadIdx.x;
    const int b   = blockIdx.y;
    const int c   = blockIdx.z;
    const int t0  = blockIdx.x * (TPB * TT) + tid;
    const int t1  = t0 + TPB;
    const int tc0 = (t0 < TSTEPS) ? t0 : (TSTEPS - 1);
    const int tc1 = (t1 < TSTEPS) ? t1 : (TSTEPS - 1);

    __shared__ union {
        float projS[NMELS * DDIM];    // 20 KB, phase 1 only
        float cbS[2][KT * DDIM];      // 32 KB, phase 2 only
    } sh;
    __shared__ float invn[KCB];       // 4 KB

    const float* cbc = cb + (size_t)c * KCB * DDIM;

    // ---- stage proj[c] into LDS ----
    {
        const float4* src = (const float4*)(proj + (size_t)c * NMELS * DDIM);
        float4* dst = (float4*)sh.projS;
        for (int i = tid; i < NMELS * DDIM / 4; i += TPB) dst[i] = src[i];
    }

    // ---- codebook inverse norms ----
    for (int j = 0; j < KCB / TPB; ++j) {
        const int k = j * TPB + tid;
        const float4* r = (const float4*)(cbc + (size_t)k * DDIM);
        float s = 0.f;
        #pragma unroll
        for (int i = 0; i < DDIM / 4; ++i) {
            float4 v = r[i];
            s += v.x * v.x + v.y * v.y + v.z * v.z + v.w * v.w;
        }
        invn[k] = 1.0f / fmaxf(sqrtf(s), 1e-12f);
    }

    // ---- issue tile-0 global loads early (latency hides under phase 1) ----
    float4 r0, r1, r2, r3;
    {
        const float4* g = (const float4*)cbc;   // tile 0 = first KT rows
        r0 = g[tid];       r1 = g[tid + 256];
        r2 = g[tid + 512]; r3 = g[tid + 768];
    }

    __syncthreads();   // S1: projS + invn visible

    // ---- phase 1: P[tt][d] = sum_n mel[b,n,t_tt] * proj[c,n,d] ----
    float P0[DDIM], P1[DDIM];
    #pragma unroll
    for (int d = 0; d < DDIM; ++d) { P0[d] = 0.f; P1[d] = 0.f; }

    const float* mp = mel + (size_t)b * NMELS * TSTEPS;
    for (int n = 0; n < NMELS; ++n) {
        const float m0 = mp[(size_t)n * TSTEPS + tc0];
        const float m1 = mp[(size_t)n * TSTEPS + tc1];
        const float4* ps = (const float4*)(sh.projS + n * DDIM);
        #pragma unroll
        for (int i = 0; i < DDIM / 4; ++i) {
            float4 v = ps[i];
            P0[4*i+0] = fmaf(m0, v.x, P0[4*i+0]);
            P0[4*i+1] = fmaf(m0, v.y, P0[4*i+1]);
            P0[4*i+2] = fmaf(m0, v.z, P0[4*i+2]);
            P0[4*i+3] = fmaf(m0, v.w, P0[4*i+3]);
            P1[4*i+0] = fmaf(m1, v.x, P1[4*i+0]);
            P1[4*i+1] = fmaf(m1, v.y, P1[4*i+1]);
            P1[4*i+2] = fmaf(m1, v.z, P1[4*i+2]);
            P1[4*i+3] = fmaf(m1, v.w, P1[4*i+3]);
        }
    }

    __syncthreads();   // S2: all waves done reading projS (about to overwrite)

    // ---- write tile 0 into buf 0; prefetch tile 1 ----
    {
        float4* dst = (float4*)sh.cbS[0];
        dst[tid] = r0; dst[tid + 256] = r1; dst[tid + 512] = r2; dst[tid + 768] = r3;
    }
    {
        const float4* g = (const float4*)(cbc + (size_t)KT * DDIM);
        r0 = g[tid];       r1 = g[tid + 256];
        r2 = g[tid + 512]; r3 = g[tid + 768];
    }

    __syncthreads();   // S3: cbS[0] ready

    // ---- phase 2: streaming argmax over k ----
    float best0 = -INFINITY, best1 = -INFINITY;
    int   bi0 = 0, bi1 = 0;

    for (int kt = 0; kt < NKT; ++kt) {
        const int cur = kt & 1;
        const float* base = sh.cbS[cur];
        const int kbase = kt * KT;

        #pragma unroll 2
        for (int kk = 0; kk < KT; ++kk) {
            const float4* row = (const float4*)(base + kk * DDIM);
            float a0 = 0.f, a1 = 0.f, a2 = 0.f, a3 = 0.f;
            float b0 = 0.f, b1 = 0.f, b2 = 0.f, b3 = 0.f;
            #pragma unroll
            for (int i = 0; i < DDIM / 4; ++i) {
                float4 v = row[i];
                a0 = fmaf(P0[4*i+0], v.x, a0);
                a1 = fmaf(P0[4*i+1], v.y, a1);
                a2 = fmaf(P0[4*i+2], v.z, a2);
                a3 = fmaf(P0[4*i+3], v.w, a3);
                b0 = fmaf(P1[4*i+0], v.x, b0);
                b1 = fmaf(P1[4*i+1], v.y, b1);
                b2 = fmaf(P1[4*i+2], v.z, b2);
                b3 = fmaf(P1[4*i+3], v.w, b3);
            }
            const int k = kbase + kk;
            const float w  = invn[k];
            const float s0 = ((a0 + a1) + (a2 + a3)) * w;
            const float s1 = ((b0 + b1) + (b2 + b3)) * w;
            if (s0 > best0) { best0 = s0; bi0 = k; }   // strict >: np.argmax tie-break
            if (s1 > best1) { best1 = s1; bi1 = k; }
        }

        if (kt + 1 < NKT) {
            // write prefetched tile kt+1 into the other buffer
            float4* dst = (float4*)sh.cbS[cur ^ 1];
            dst[tid] = r0; dst[tid + 256] = r1; dst[tid + 512] = r2; dst[tid + 768] = r3;
            if (kt + 2 < NKT) {
                const float4* g = (const float4*)(cbc + (size_t)(kt + 2) * KT * DDIM);
                r0 = g[tid];       r1 = g[tid + 256];
                r2 = g[tid + 512]; r3 = g[tid + 768];
            }
        }
        __syncthreads();
    }

    const size_t obase = ((size_t)c * B + b) * TSTEPS;
    if (t0 < TSTEPS) out[obase + t0] = bi0;
    if (t1 < TSTEPS) out[obase + t1] = bi1;
}

extern "C" void kernel_launch(void* const* d_in, const int* in_sizes, int n_in,
                              void* d_out, int out_size, void* d_ws, size_t ws_size,
                              hipStream_t stream) {
    const float* mel  = (const float*)d_in[0];
    const float* proj = (const float*)d_in[1];
    const float* cb   = (const float*)d_in[2];
    int* out = (int*)d_out;

    dim3 grid((TSTEPS + TPB * TT - 1) / (TPB * TT), B, NCB);  // (8, 32, 2) = 512 blocks
    dim3 block(TPB);
    rpq_kernel<<<grid, block, 0, stream>>>(mel, proj, cb, out);
}

// Round 5
// 319.571 us; speedup vs baseline: 2.0594x; 1.5908x over previous
//
#include <hip/hip_runtime.h>
#include <hip/hip_bf16.h>
#include <math.h>
#include <stdint.h>

// RandomProjectionQuantizer — bf16 MFMA filter + exact fp32 top-8 rescore.
//   mel [32,80,4000] f32, proj [2,80,64] f32, codebooks [2,1024,64] f32
//   codes[c,b,t] = argmax_k ( (mel[b,:,t] @ proj[c]) . cb[c,k,:]/||cb[c,k]|| )
// p-normalization dropped (positive, const over k). cb norm folded to invn[k]
// applied to filter sims AND exact rescore. Filter: bf16 16x16x32 MFMA
// (m91/m92-verified fragment layouts: A,B k-contiguous-8/lane; C col=lane&15,
// row=(lane>>4)*4+reg). Per-lane packed top-2 (low 10 mantissa bits = 1023-k),
// merged to top-8 per t, rescored exactly in fp32 (np.argmax tie-break k<).
// Single kernel: no prep, no workspace, no global_load_lds, reg-staged
// XOR-swizzled LDS tiles (m214 pattern), R3-proven double-buffer schedule.

#define B      32
#define NMELS  80
#define TSTEPS 4000
#define NCB    2
#define KCB    1024
#define DDIM   64
#define TPB    256
#define TM     64            // t's per block (16 per wave)
#define KT     64            // codebook rows per LDS tile (8 KB bf16)
#define NKT    (KCB / KT)    // 16 tiles
#define PPAD   68            // P row stride (floats), 16B-aligned

typedef short bf16x8 __attribute__((ext_vector_type(8)));
typedef float f32x4  __attribute__((ext_vector_type(4)));

static __device__ __forceinline__ uint32_t bits(float f) {
    return __builtin_bit_cast(uint32_t, f);
}
static __device__ __forceinline__ float fbits(uint32_t u) {
    return __builtin_bit_cast(float, u);
}
// truncating f32->bf16 pair pack (a -> low half, b -> high half)
static __device__ __forceinline__ uint32_t pack_bf16(float a, float b) {
    return (bits(a) >> 16) | (bits(b) & 0xFFFF0000u);
}

__global__ __launch_bounds__(TPB, 2) void rpq_kernel(
    const float* __restrict__ mel,
    const float* __restrict__ proj,
    const float* __restrict__ cb,
    int* __restrict__ out)
{
    const int tid  = threadIdx.x;
    const int b    = blockIdx.y;
    const int c    = blockIdx.z;
    const int t0   = blockIdx.x * TM;

    const int l    = tid & 63;
    const int wid  = tid >> 6;      // wave 0..3
    const int lrow = l & 15;        // A/B row-col within 16x16
    const int lgrp = l >> 4;        // k-octet group 0..3

    __shared__ union __align__(16) {
        float projS[NMELS * DDIM];     // 20480 B (phase 1)
        char  cbuf[2][KT * 128];       // 16384 B (filter bf16 dbuf)
    } U;
    __shared__ float    invn[KCB];     // 4096 B
    __shared__ float    PL[TM * PPAD]; // 17408 B
    __shared__ uint32_t cand[TM][17][2]; // 8704 B (pad 17 vs bank conflicts)
    __shared__ float    scv[TM][8];    // 2048 B
    __shared__ int      sck[TM][8];    // 2048 B   -> total 54784 B

    const float* cbc = cb + (size_t)c * KCB * DDIM;

    // ---- stage proj[c] into LDS ----
    {
        const float4* src = (const float4*)(proj + (size_t)c * NMELS * DDIM);
        float4* dst = (float4*)U.projS;
        for (int i = tid; i < NMELS * DDIM / 4; i += TPB) dst[i] = src[i];
    }
    // ---- codebook inverse norms (R3-proven) ----
    for (int j = 0; j < KCB / TPB; ++j) {
        const int k = j * TPB + tid;
        const float4* r = (const float4*)(cbc + (size_t)k * DDIM);
        float s = 0.f;
        #pragma unroll
        for (int i = 0; i < DDIM / 4; ++i) {
            float4 v = r[i];
            s += v.x * v.x + v.y * v.y + v.z * v.z + v.w * v.w;
        }
        invn[k] = 1.0f / fmaxf(sqrtf(s), 1e-12f);
    }
    __syncthreads();                                  // S1

    // ---- issue tile-0 global loads early (latency hides under phase 1) ----
    const int srow = tid >> 2;     // staging row 0..63
    const int sq   = tid & 3;      // staging quarter (16 floats)
    float4 g0, g1, g2, g3;
    {
        const float4* gp = (const float4*)(cbc + (size_t)srow * DDIM + sq * 16);
        g0 = gp[0]; g1 = gp[1]; g2 = gp[2]; g3 = gp[3];
    }

    // ---- phase 1: P[t][d] fp32; thread = (t = tid&63, d-quarter = tid>>6) ----
    {
        const int tl = tid & 63, dq = tid >> 6;
        const int tg = t0 + tl;
        const int tc = (tg < TSTEPS) ? tg : (TSTEPS - 1);
        float Pa[16];
        #pragma unroll
        for (int i = 0; i < 16; ++i) Pa[i] = 0.f;
        const float* mp = mel + (size_t)b * NMELS * TSTEPS + tc;
        for (int n = 0; n < NMELS; ++n) {
            const float m = mp[(size_t)n * TSTEPS];
            const float* ps = &U.projS[n * DDIM + dq * 16];
            #pragma unroll
            for (int i = 0; i < 16; ++i) Pa[i] = fmaf(m, ps[i], Pa[i]);
        }
        __syncthreads();                              // S2: projS reads done
        #pragma unroll
        for (int i = 0; i < 16; i += 4)
            *(float4*)&PL[tl * PPAD + dq * 16 + i] =
                make_float4(Pa[i], Pa[i+1], Pa[i+2], Pa[i+3]);
    }

    // ---- write tile 0 (f32->bf16, XOR-swizzled rows) into cbuf[0] ----
    {
        const int xw = (srow & 7) << 4;
        const float f[16] = {g0.x,g0.y,g0.z,g0.w, g1.x,g1.y,g1.z,g1.w,
                             g2.x,g2.y,g2.z,g2.w, g3.x,g3.y,g3.z,g3.w};
        uint32_t dw[8];
        #pragma unroll
        for (int m = 0; m < 8; ++m) dw[m] = pack_bf16(f[2*m], f[2*m+1]);
        char* base = &U.cbuf[0][srow * 128];
        *(uint4*)(base + ((sq * 32)      ^ xw)) = make_uint4(dw[0],dw[1],dw[2],dw[3]);
        *(uint4*)(base + ((sq * 32 + 16) ^ xw)) = make_uint4(dw[4],dw[5],dw[6],dw[7]);
    }
    __syncthreads();                                  // S3: PL + tile0 ready

    // ---- A fragments (bf16, truncated) from PL ----
    bf16x8 A0, A1;
    {
        const float* pr = &PL[((wid << 4) + lrow) * PPAD];
        #pragma unroll
        for (int i = 0; i < 8; ++i) {
            A0[i] = (short)(bits(pr[lgrp * 8 + i]) >> 16);        // d 0..31
            A1[i] = (short)(bits(pr[32 + lgrp * 8 + i]) >> 16);   // d 32..63
        }
    }

    // ---- filter loop over 16 tiles ----
    float m1[4], m2[4];
    #pragma unroll
    for (int r = 0; r < 4; ++r) { m1[r] = -INFINITY; m2[r] = -INFINITY; }
    uint32_t idxv = (uint32_t)(1023 - lrow);  // 1023 - k payload

    const int xr = (lrow & 7) << 4;           // read swizzle (row&7 == lrow&7)
    const int bo0 = (lgrp * 16) ^ xr;
    const int bo1 = (64 + lgrp * 16) ^ xr;

    for (int kt = 0; kt < NKT; ++kt) {
        const int cur = kt & 1;
        if (kt + 1 < NKT) {   // issue next-tile global loads (f32)
            const float4* gp = (const float4*)(cbc + (size_t)(kt + 1) * KT * DDIM
                                               + (size_t)srow * DDIM + sq * 16);
            g0 = gp[0]; g1 = gp[1]; g2 = gp[2]; g3 = gp[3];
        }
        const char* buf = U.cbuf[cur];
        const int kb = kt * KT;
        #pragma unroll
        for (int s = 0; s < 4; ++s) {
            const char* rowp = buf + (s * 16 + lrow) * 128;
            bf16x8 B0 = *(const bf16x8*)(rowp + bo0);
            bf16x8 B1 = *(const bf16x8*)(rowp + bo1);
            f32x4 acc = {0.f, 0.f, 0.f, 0.f};
            acc = __builtin_amdgcn_mfma_f32_16x16x32_bf16(A0, B0, acc, 0, 0, 0);
            acc = __builtin_amdgcn_mfma_f32_16x16x32_bf16(A1, B1, acc, 0, 0, 0);
            const float w = invn[kb + s * 16 + lrow];
            #pragma unroll
            for (int r = 0; r < 4; ++r) {
                const float sv = acc[r] * w;
                const float pf = fbits((bits(sv) & 0xFFFFFC00u) | idxv);
                m2[r] = fmaxf(fminf(pf, m1[r]), m2[r]);
                m1[r] = fmaxf(pf, m1[r]);
            }
            idxv -= 16u;
        }
        if (kt + 1 < NKT) {   // convert + write next tile into other buffer
            const int xw = (srow & 7) << 4;
            const float f[16] = {g0.x,g0.y,g0.z,g0.w, g1.x,g1.y,g1.z,g1.w,
                                 g2.x,g2.y,g2.z,g2.w, g3.x,g3.y,g3.z,g3.w};
            uint32_t dw[8];
            #pragma unroll
            for (int m = 0; m < 8; ++m) dw[m] = pack_bf16(f[2*m], f[2*m+1]);
            char* base = &U.cbuf[cur ^ 1][srow * 128];
            *(uint4*)(base + ((sq * 32)      ^ xw)) = make_uint4(dw[0],dw[1],dw[2],dw[3]);
            *(uint4*)(base + ((sq * 32 + 16) ^ xw)) = make_uint4(dw[4],dw[5],dw[6],dw[7]);
        }
        __syncthreads();
    }

    // ---- per-lane top-2 -> cand; C row t = wid*16 + lgrp*4 + r (m89) ----
    #pragma unroll
    for (int r = 0; r < 4; ++r) {
        const int trow = (wid << 4) + (lgrp << 2) + r;
        cand[trow][lrow][0] = bits(m1[r]);
        cand[trow][lrow][1] = bits(m2[r]);
    }
    __syncthreads();                                  // S4

    // ---- merge top-8 per t (4 threads/t compute redundantly), rescore 2 each ----
    {
        const int t = tid & 63;
        const int j = wid;
        float c1 = -INFINITY, c2 = -INFINITY, c3 = -INFINITY, c4 = -INFINITY;
        float c5 = -INFINITY, c6 = -INFINITY, c7 = -INFINITY, c8 = -INFINITY;
        for (int i = 0; i < 16; ++i) {
            #pragma unroll
            for (int jj = 0; jj < 2; ++jj) {
                const float p = fbits(cand[t][i][jj]);
                c8 = fmaxf(fminf(p, c7), c8);
                c7 = fmaxf(fminf(p, c6), c7);
                c6 = fmaxf(fminf(p, c5), c6);
                c5 = fmaxf(fminf(p, c4), c5);
                c4 = fmaxf(fminf(p, c3), c4);
                c3 = fmaxf(fminf(p, c2), c3);
                c2 = fmaxf(fminf(p, c1), c2);
                c1 = fmaxf(p, c1);
            }
        }
        const float sel0 = (j == 0) ? c1 : (j == 1) ? c3 : (j == 2) ? c5 : c7;
        const float sel1 = (j == 0) ? c2 : (j == 1) ? c4 : (j == 2) ? c6 : c8;
        const float* pr = &PL[t * PPAD];
        #pragma unroll
        for (int e = 0; e < 2; ++e) {
            const float sel = e ? sel1 : sel0;
            const int kj = 1023 - (int)(bits(sel) & 0x3FFu);
            const float* cbr = cbc + (size_t)kj * DDIM;
            float a0 = 0.f, a1 = 0.f, a2 = 0.f, a3 = 0.f;
            #pragma unroll
            for (int i = 0; i < 16; ++i) {
                float4 pv = *(const float4*)(pr + i * 4);
                float4 cv = *(const float4*)(cbr + i * 4);
                a0 = fmaf(pv.x, cv.x, a0); a1 = fmaf(pv.y, cv.y, a1);
                a2 = fmaf(pv.z, cv.z, a2); a3 = fmaf(pv.w, cv.w, a3);
            }
            scv[t][2*j + e] = ((a0 + a1) + (a2 + a3)) * invn[kj];
            sck[t][2*j + e] = kj;
        }
    }
    __syncthreads();                                  // S5

    if (tid < TM) {
        const int tg = t0 + tid;
        if (tg < TSTEPS) {
            float best = scv[tid][0];
            int   bk   = sck[tid][0];
            #pragma unroll
            for (int s2 = 1; s2 < 8; ++s2) {
                const float v = scv[tid][s2];
                const int  kk = sck[tid][s2];
                if (v > best || (v == best && kk < bk)) { best = v; bk = kk; }
            }
            out[((size_t)c * B + b) * TSTEPS + tg] = bk;
        }
    }
}

extern "C" void kernel_launch(void* const* d_in, const int* in_sizes, int n_in,
                              void* d_out, int out_size, void* d_ws, size_t ws_size,
                              hipStream_t stream) {
    const float* mel  = (const float*)d_in[0];
    const float* proj = (const float*)d_in[1];
    const float* cb   = (const float*)d_in[2];
    int* out = (int*)d_out;

    dim3 grid((TSTEPS + TM - 1) / TM, B, NCB);   // (63, 32, 2)
    dim3 block(TPB);
    rpq_kernel<<<grid, block, 0, stream>>>(mel, proj, cb, out);
}

// Round 6
// 175.532 us; speedup vs baseline: 3.7494x; 1.8206x over previous
//
#include <hip/hip_runtime.h>
#include <hip/hip_bf16.h>
#include <math.h>
#include <stdint.h>

// RandomProjectionQuantizer — bf16 MFMA filter + exact fp32 top-8 rescore.
//   mel [32,80,4000] f32, proj [2,80,64] f32, codebooks [2,1024,64] f32
//   codes[c,b,t] = argmax_k ( (mel[b,:,t] @ proj[c]) . cb[c,k,:]/||cb[c,k]|| )
//
// R6 vs R5 (proven): prep kernel writes invn + NORMALIZED RNE-bf16 codebook to
// d_ws (ws_size >= 270336 proven by R4's branch); per-block invn recompute and
// f32->bf16 packing removed; LDS 54.8K->50.2K via PL/cbuf/projS union -> 3
// blocks/CU (12 waves); fmed3 top-2 update. Filter LDS layout, swizzle, MFMA
// fragment mapping, cand/merge/rescore logic are UNCHANGED from R5.

#define B      32
#define NMELS  80
#define TSTEPS 4000
#define NCB    2
#define KCB    1024
#define DDIM   64
#define TPB    256
#define TM     64            // t's per block (16 per wave)
#define KT     64            // codebook rows per LDS tile (8 KB bf16)
#define NKT    (KCB / KT)    // 16 tiles
#define PPAD   66            // P row stride (floats)

typedef short bf16x8 __attribute__((ext_vector_type(8)));
typedef float f32x4  __attribute__((ext_vector_type(4)));

#define WS_CB_OFF   8192                         // bytes: invn table first
#define WS_NEEDED   (8192 + NCB*KCB*DDIM*2)      // 270336 (== R4's, proven fits)

static __device__ __forceinline__ uint32_t bits(float f) {
    return __builtin_bit_cast(uint32_t, f);
}
static __device__ __forceinline__ float fbits(uint32_t u) {
    return __builtin_bit_cast(float, u);
}
// round-to-nearest-even f32 -> bf16 (returns low 16 bits)
static __device__ __forceinline__ uint32_t rne16(uint32_t u) {
    return (u + 0x7FFFu + ((u >> 16) & 1u)) >> 16;
}

// ---------------------------------------------------------------- prep ----
// one thread per codebook row: invn[c*1024+k] and normalized bf16 row (RNE),
// linear (unswizzled) layout; swizzle is applied at ds_write in main (as R5).
__global__ __launch_bounds__(TPB) void rpq_prep(const float* __restrict__ cb,
                                                float* __restrict__ ws)
{
    const int idx = blockIdx.x * TPB + threadIdx.x;
    if (idx >= NCB * KCB) return;

    const float4* row = (const float4*)(cb + (size_t)idx * DDIM);
    float4 v[16];
    float ss = 0.f;
    #pragma unroll
    for (int i = 0; i < 16; ++i) {
        v[i] = row[i];
        ss += v[i].x*v[i].x + v[i].y*v[i].y + v[i].z*v[i].z + v[i].w*v[i].w;
    }
    const float inv = 1.0f / fmaxf(sqrtf(ss), 1e-12f);
    ws[idx] = inv;

    uint32_t dw[32];
    #pragma unroll
    for (int i = 0; i < 16; ++i) {
        dw[2*i]   = rne16(bits(v[i].x * inv)) | (rne16(bits(v[i].y * inv)) << 16);
        dw[2*i+1] = rne16(bits(v[i].z * inv)) | (rne16(bits(v[i].w * inv)) << 16);
    }
    uint4* dst = (uint4*)((char*)ws + WS_CB_OFF + (size_t)idx * 128);
    #pragma unroll
    for (int i = 0; i < 8; ++i)
        dst[i] = make_uint4(dw[4*i], dw[4*i+1], dw[4*i+2], dw[4*i+3]);
}

// ---------------------------------------------------------------- main ----
__global__ __launch_bounds__(TPB, 3) void rpq_main(
    const float* __restrict__ mel,
    const float* __restrict__ proj,
    const float* __restrict__ cb,
    const float* __restrict__ ws,
    int* __restrict__ out)
{
    const int tid  = threadIdx.x;
    const int b    = blockIdx.y;
    const int c    = blockIdx.z;
    const int t0   = blockIdx.x * TM;

    const int l    = tid & 63;
    const int wid  = tid >> 6;      // wave 0..3
    const int lrow = l & 15;        // A/B row-col within 16x16
    const int lgrp = l >> 4;        // k-octet group 0..3

    // projS is phase-1-only; cbuf+PL written strictly after S2 barrier.
    __shared__ union __align__(16) {
        float projS[NMELS * DDIM];          // 20480 B
        struct {
            char  cbuf[2][KT * 128];        // 16384 B (bf16 dbuf, swizzled)
            float PL[TM * PPAD];            // 16896 B (P fp32)
        } p2;
    } U;                                    // union: 33280 B
    __shared__ float    invnS[KCB];         // 4096 B
    __shared__ uint32_t cand[TM][17][2];    // 8704 B
    __shared__ float    scv[TM][8];         // 2048 B
    __shared__ int      sck[TM][8];         // 2048 B  -> total 50176 B

    const char* wscb = (const char*)ws + WS_CB_OFF + (size_t)c * (KCB * 128);

    // ---- stage proj[c] + invn slice into LDS ----
    {
        const float4* src = (const float4*)(proj + (size_t)c * NMELS * DDIM);
        float4* dst = (float4*)U.projS;
        for (int i = tid; i < NMELS * DDIM / 4; i += TPB) dst[i] = src[i];
        *(float4*)&invnS[4 * tid] = *(const float4*)(ws + (size_t)c * KCB + 4 * tid);
    }
    __syncthreads();                                  // S1

    // ---- issue tile-0 staging loads early (bf16, coalesced 32B/thread) ----
    const int srow = tid >> 2;     // staging row 0..63
    const int sq   = tid & 3;      // 32-byte quarter
    uint4 g0, g1;
    {
        const uint4* gp = (const uint4*)(wscb + (size_t)srow * 128 + sq * 32);
        g0 = gp[0]; g1 = gp[1];
    }

    // ---- phase 1: P[t][d] fp32; thread = (t = tid&63, d-quarter = tid>>6) ----
    {
        const int tl = tid & 63, dq = tid >> 6;
        const int tg = t0 + tl;
        const int tc = (tg < TSTEPS) ? tg : (TSTEPS - 1);
        float Pa[16];
        #pragma unroll
        for (int i = 0; i < 16; ++i) Pa[i] = 0.f;
        const float* mp = mel + (size_t)b * NMELS * TSTEPS + tc;
        for (int n = 0; n < NMELS; ++n) {
            const float m = mp[(size_t)n * TSTEPS];
            const float* ps = &U.projS[n * DDIM + dq * 16];
            #pragma unroll
            for (int i = 0; i < 16; ++i) Pa[i] = fmaf(m, ps[i], Pa[i]);
        }
        __syncthreads();                              // S2: projS reads done
        #pragma unroll
        for (int i = 0; i < 16; i += 4)
            *(float4*)&U.p2.PL[tl * PPAD + dq * 16 + i] =
                make_float4(Pa[i], Pa[i+1], Pa[i+2], Pa[i+3]);
    }

    // ---- write tile 0 (XOR-swizzled rows, identical addressing to R5) ----
    {
        const int xw = (srow & 7) << 4;
        char* base = &U.p2.cbuf[0][srow * 128];
        *(uint4*)(base + ((sq * 32)      ^ xw)) = g0;
        *(uint4*)(base + ((sq * 32 + 16) ^ xw)) = g1;
    }
    __syncthreads();                                  // S3: PL + tile0 ready

    // ---- A fragments (bf16 RNE) from PL ----
    bf16x8 A0, A1;
    {
        const float* pr = &U.p2.PL[((wid << 4) + lrow) * PPAD];
        #pragma unroll
        for (int i = 0; i < 8; ++i) {
            A0[i] = (short)rne16(bits(pr[lgrp * 8 + i]));        // d 0..31
            A1[i] = (short)rne16(bits(pr[32 + lgrp * 8 + i]));   // d 32..63
        }
    }

    // ---- filter loop over 16 tiles (sims are pre-normalized) ----
    float m1[4], m2[4];
    #pragma unroll
    for (int r = 0; r < 4; ++r) { m1[r] = -INFINITY; m2[r] = -INFINITY; }
    uint32_t idxv = (uint32_t)(1023 - lrow);  // payload = 1023 - k

    const int xr  = (lrow & 7) << 4;
    const int bo0 = (lgrp * 16) ^ xr;
    const int bo1 = (64 + lgrp * 16) ^ xr;

    for (int kt = 0; kt < NKT; ++kt) {
        const int cur = kt & 1;
        if (kt + 1 < NKT) {   // issue next-tile staging loads (bf16 from ws)
            const uint4* gp = (const uint4*)(wscb + (size_t)(kt + 1) * (KT * 128)
                                             + (size_t)srow * 128 + sq * 32);
            g0 = gp[0]; g1 = gp[1];
        }
        const char* buf = U.p2.cbuf[cur];
        #pragma unroll
        for (int s = 0; s < 4; ++s) {
            const char* rowp = buf + (s * 16 + lrow) * 128;
            bf16x8 B0 = *(const bf16x8*)(rowp + bo0);
            bf16x8 B1 = *(const bf16x8*)(rowp + bo1);
            f32x4 acc = {0.f, 0.f, 0.f, 0.f};
            acc = __builtin_amdgcn_mfma_f32_16x16x32_bf16(A0, B0, acc, 0, 0, 0);
            acc = __builtin_amdgcn_mfma_f32_16x16x32_bf16(A1, B1, acc, 0, 0, 0);
            #pragma unroll
            for (int r = 0; r < 4; ++r) {
                const float pf = fbits((bits(acc[r]) & 0xFFFFFC00u) | idxv);
                m2[r] = __builtin_amdgcn_fmed3f(pf, m1[r], m2[r]);
                m1[r] = fmaxf(pf, m1[r]);
            }
            idxv -= 16u;
        }
        if (kt + 1 < NKT) {   // write next tile into other buffer (R5 pattern)
            const int xw = (srow & 7) << 4;
            char* base = &U.p2.cbuf[cur ^ 1][srow * 128];
            *(uint4*)(base + ((sq * 32)      ^ xw)) = g0;
            *(uint4*)(base + ((sq * 32 + 16) ^ xw)) = g1;
        }
        __syncthreads();
    }

    // ---- per-lane top-2 -> cand; C row t = wid*16 + lgrp*4 + r (m89) ----
    #pragma unroll
    for (int r = 0; r < 4; ++r) {
        const int trow = (wid << 4) + (lgrp << 2) + r;
        cand[trow][lrow][0] = bits(m1[r]);
        cand[trow][lrow][1] = bits(m2[r]);
    }
    __syncthreads();                                  // S4

    // ---- merge top-8 per t (4 threads/t redundantly), rescore 2 each ----
    {
        const int t = tid & 63;
        const int j = wid;
        float c1 = -INFINITY, c2 = -INFINITY, c3 = -INFINITY, c4 = -INFINITY;
        float c5 = -INFINITY, c6 = -INFINITY, c7 = -INFINITY, c8 = -INFINITY;
        for (int i = 0; i < 16; ++i) {
            #pragma unroll
            for (int jj = 0; jj < 2; ++jj) {
                const float p = fbits(cand[t][i][jj]);
                c8 = fmaxf(fminf(p, c7), c8);
                c7 = fmaxf(fminf(p, c6), c7);
                c6 = fmaxf(fminf(p, c5), c6);
                c5 = fmaxf(fminf(p, c4), c5);
                c4 = fmaxf(fminf(p, c3), c4);
                c3 = fmaxf(fminf(p, c2), c3);
                c2 = fmaxf(fminf(p, c1), c2);
                c1 = fmaxf(p, c1);
            }
        }
        const float sel0 = (j == 0) ? c1 : (j == 1) ? c3 : (j == 2) ? c5 : c7;
        const float sel1 = (j == 0) ? c2 : (j == 1) ? c4 : (j == 2) ? c6 : c8;
        const float* pr = &U.p2.PL[t * PPAD];
        const float* cbc = cb + (size_t)c * KCB * DDIM;
        #pragma unroll
        for (int e = 0; e < 2; ++e) {
            const float sel = e ? sel1 : sel0;
            const int kj = 1023 - (int)(bits(sel) & 0x3FFu);
            const float* cbr = cbc + (size_t)kj * DDIM;
            float a0 = 0.f, a1 = 0.f, a2 = 0.f, a3 = 0.f;
            #pragma unroll
            for (int i = 0; i < 16; ++i) {
                float4 pv = *(const float4*)(pr + i * 4);
                float4 cv = *(const float4*)(cbr + i * 4);
                a0 = fmaf(pv.x, cv.x, a0); a1 = fmaf(pv.y, cv.y, a1);
                a2 = fmaf(pv.z, cv.z, a2); a3 = fmaf(pv.w, cv.w, a3);
            }
            scv[t][2*j + e] = ((a0 + a1) + (a2 + a3)) * invnS[kj];
            sck[t][2*j + e] = kj;
        }
    }
    __syncthreads();                                  // S5

    if (tid < TM) {
        const int tg = t0 + tid;
        if (tg < TSTEPS) {
            float best = scv[tid][0];
            int   bk   = sck[tid][0];
            #pragma unroll
            for (int s2 = 1; s2 < 8; ++s2) {
                const float v = scv[tid][s2];
                const int  kk = sck[tid][s2];
                if (v > best || (v == best && kk < bk)) { best = v; bk = kk; }
            }
            out[((size_t)c * B + b) * TSTEPS + tg] = bk;
        }
    }
}

// ------------------------------------------------------------- fallback ----
// R5 kernel essentials are preserved above; if ws is unexpectedly small we
// cannot run the prep path — use the R3-style proven pure-VALU kernel.
__global__ __launch_bounds__(TPB, 2) void rpq_fallback(
    const float* __restrict__ mel, const float* __restrict__ proj,
    const float* __restrict__ cb, int* __restrict__ out)
{
    const int tid = threadIdx.x;
    const int b = blockIdx.y, c = blockIdx.z;
    const int t0 = blockIdx.x * (TPB * 2) + tid;
    const int t1 = t0 + TPB;
    const int tc0 = (t0 < TSTEPS) ? t0 : (TSTEPS - 1);
    const int tc1 = (t1 < TSTEPS) ? t1 : (TSTEPS - 1);

    __shared__ union { float projS[NMELS*DDIM]; float cbS[2][64*DDIM]; } sh;
    __shared__ float invn[KCB];
    const float* cbc = cb + (size_t)c * KCB * DDIM;
    {
        const float4* src = (const float4*)(proj + (size_t)c * NMELS * DDIM);
        float4* dst = (float4*)sh.projS;
        for (int i = tid; i < NMELS*DDIM/4; i += TPB) dst[i] = src[i];
    }
    for (int j = 0; j < KCB/TPB; ++j) {
        const int k = j*TPB + tid;
        const float4* r = (const float4*)(cbc + (size_t)k * DDIM);
        float s = 0.f;
        #pragma unroll
        for (int i = 0; i < DDIM/4; ++i) {
            float4 v = r[i]; s += v.x*v.x + v.y*v.y + v.z*v.z + v.w*v.w;
        }
        invn[k] = 1.0f / fmaxf(sqrtf(s), 1e-12f);
    }
    float4 r0, r1, r2, r3;
    { const float4* g = (const float4*)cbc;
      r0 = g[tid]; r1 = g[tid+256]; r2 = g[tid+512]; r3 = g[tid+768]; }
    __syncthreads();
    float P0[DDIM], P1[DDIM];
    #pragma unroll
    for (int d = 0; d < DDIM; ++d) { P0[d] = 0.f; P1[d] = 0.f; }
    const float* mp = mel + (size_t)b * NMELS * TSTEPS;
    for (int n = 0; n < NMELS; ++n) {
        const float m0 = mp[(size_t)n*TSTEPS + tc0];
        const float m1_ = mp[(size_t)n*TSTEPS + tc1];
        const float4* ps = (const float4*)(sh.projS + n*DDIM);
        #pragma unroll
        for (int i = 0; i < DDIM/4; ++i) {
            float4 v = ps[i];
            P0[4*i+0]=fmaf(m0,v.x,P0[4*i+0]); P0[4*i+1]=fmaf(m0,v.y,P0[4*i+1]);
            P0[4*i+2]=fmaf(m0,v.z,P0[4*i+2]); P0[4*i+3]=fmaf(m0,v.w,P0[4*i+3]);
            P1[4*i+0]=fmaf(m1_,v.x,P1[4*i+0]); P1[4*i+1]=fmaf(m1_,v.y,P1[4*i+1]);
            P1[4*i+2]=fmaf(m1_,v.z,P1[4*i+2]); P1[4*i+3]=fmaf(m1_,v.w,P1[4*i+3]);
        }
    }
    __syncthreads();
    { float4* dst = (float4*)sh.cbS[0];
      dst[tid]=r0; dst[tid+256]=r1; dst[tid+512]=r2; dst[tid+768]=r3; }
    { const float4* g = (const float4*)(cbc + (size_t)64*DDIM);
      r0=g[tid]; r1=g[tid+256]; r2=g[tid+512]; r3=g[tid+768]; }
    __syncthreads();
    float best0 = -INFINITY, best1 = -INFINITY; int bi0 = 0, bi1 = 0;
    for (int kt = 0; kt < KCB/64; ++kt) {
        const int cur = kt & 1;
        const float* base = sh.cbS[cur];
        const int kbase = kt * 64;
        #pragma unroll 2
        for (int kk = 0; kk < 64; ++kk) {
            const float4* row = (const float4*)(base + kk*DDIM);
            float a0=0,a1=0,a2=0,a3=0,b0=0,b1=0,b2=0,b3=0;
            #pragma unroll
            for (int i = 0; i < DDIM/4; ++i) {
                float4 v = row[i];
                a0=fmaf(P0[4*i+0],v.x,a0); a1=fmaf(P0[4*i+1],v.y,a1);
                a2=fmaf(P0[4*i+2],v.z,a2); a3=fmaf(P0[4*i+3],v.w,a3);
                b0=fmaf(P1[4*i+0],v.x,b0); b1=fmaf(P1[4*i+1],v.y,b1);
                b2=fmaf(P1[4*i+2],v.z,b2); b3=fmaf(P1[4*i+3],v.w,b3);
            }
            const int k = kbase + kk;
            const float w = invn[k];
            const float s0 = ((a0+a1)+(a2+a3))*w;
            const float s1 = ((b0+b1)+(b2+b3))*w;
            if (s0 > best0) { best0 = s0; bi0 = k; }
            if (s1 > best1) { best1 = s1; bi1 = k; }
        }
        if (kt + 1 < KCB/64) {
            float4* dst = (float4*)sh.cbS[cur ^ 1];
            dst[tid]=r0; dst[tid+256]=r1; dst[tid+512]=r2; dst[tid+768]=r3;
            if (kt + 2 < KCB/64) {
                const float4* g = (const float4*)(cbc + (size_t)(kt+2)*64*DDIM);
                r0=g[tid]; r1=g[tid+256]; r2=g[tid+512]; r3=g[tid+768];
            }
        }
        __syncthreads();
    }
    const size_t ob = ((size_t)c * B + b) * TSTEPS;
    if (t0 < TSTEPS) out[ob + t0] = bi0;
    if (t1 < TSTEPS) out[ob + t1] = bi1;
}

// --------------------------------------------------------------- launch ----
extern "C" void kernel_launch(void* const* d_in, const int* in_sizes, int n_in,
                              void* d_out, int out_size, void* d_ws, size_t ws_size,
                              hipStream_t stream) {
    const float* mel  = (const float*)d_in[0];
    const float* proj = (const float*)d_in[1];
    const float* cb   = (const float*)d_in[2];
    int* out = (int*)d_out;

    if (ws_size >= (size_t)WS_NEEDED) {   // proven true on this harness (R4)
        float* ws = (float*)d_ws;
        rpq_prep<<<dim3((NCB*KCB + TPB - 1)/TPB), dim3(TPB), 0, stream>>>(cb, ws);
        dim3 grid((TSTEPS + TM - 1) / TM, B, NCB);     // (63, 32, 2)
        rpq_main<<<grid, dim3(TPB), 0, stream>>>(mel, proj, cb, ws, out);
    } else {
        dim3 grid((TSTEPS + TPB*2 - 1) / (TPB*2), B, NCB);
        rpq_fallback<<<grid, dim3(TPB), 0, stream>>>(mel, proj, cb, out);
    }
}

// Round 7
// 167.696 us; speedup vs baseline: 3.9245x; 1.0467x over previous
//
#include <hip/hip_runtime.h>
#include <hip/hip_bf16.h>
#include <math.h>
#include <stdint.h>

// RandomProjectionQuantizer — bf16 MFMA filter + exact fp32 top-8 rescore.
//   mel [32,80,4000] f32, proj [2,80,64] f32, codebooks [2,1024,64] f32
//   codes[c,b,t] = argmax_k ( (mel[b,:,t] @ proj[c]) . cb[c,k,:]/||cb[c,k]|| )
//
// R7 vs R6 (proven, 176us): (1) phase-1 remapped to 4t x 4d per thread:
// mel float4 loads, proj lane-distinct ds_read_b128 -> 80 LDS issues/wave
// (was 320 broadcast b128 = 4x the RF writeback). (2) LDS 50176->33280 B:
// invnS dropped (rescore reads invn from L2), cand/scv/sck overlaid into the
// cbuf region (dead after filter's final barrier) -> 4 blocks/CU.
// Filter (staging, swizzle, MFMA mapping, top-2, merge, rescore) unchanged.

#define B      32
#define NMELS  80
#define TSTEPS 4000
#define NCB    2
#define KCB    1024
#define DDIM   64
#define TPB    256
#define TM     64            // t's per block (16 per wave)
#define KT     64            // codebook rows per LDS tile (8 KB bf16)
#define NKT    (KCB / KT)    // 16 tiles
#define PPAD   66            // P row stride (floats) — R6-proven

typedef short bf16x8 __attribute__((ext_vector_type(8)));
typedef float f32x4  __attribute__((ext_vector_type(4)));

#define WS_CB_OFF   8192                         // bytes: invn table first
#define WS_NEEDED   (8192 + NCB*KCB*DDIM*2)      // 270336 (proven fits, R4)

static __device__ __forceinline__ uint32_t bits(float f) {
    return __builtin_bit_cast(uint32_t, f);
}
static __device__ __forceinline__ float fbits(uint32_t u) {
    return __builtin_bit_cast(float, u);
}
// round-to-nearest-even f32 -> bf16 (returns low 16 bits)
static __device__ __forceinline__ uint32_t rne16(uint32_t u) {
    return (u + 0x7FFFu + ((u >> 16) & 1u)) >> 16;
}

// ---------------------------------------------------------------- prep ----
__global__ __launch_bounds__(TPB) void rpq_prep(const float* __restrict__ cb,
                                                float* __restrict__ ws)
{
    const int idx = blockIdx.x * TPB + threadIdx.x;
    if (idx >= NCB * KCB) return;

    const float4* row = (const float4*)(cb + (size_t)idx * DDIM);
    float4 v[16];
    float ss = 0.f;
    #pragma unroll
    for (int i = 0; i < 16; ++i) {
        v[i] = row[i];
        ss += v[i].x*v[i].x + v[i].y*v[i].y + v[i].z*v[i].z + v[i].w*v[i].w;
    }
    const float inv = 1.0f / fmaxf(sqrtf(ss), 1e-12f);
    ws[idx] = inv;

    uint32_t dw[32];
    #pragma unroll
    for (int i = 0; i < 16; ++i) {
        dw[2*i]   = rne16(bits(v[i].x * inv)) | (rne16(bits(v[i].y * inv)) << 16);
        dw[2*i+1] = rne16(bits(v[i].z * inv)) | (rne16(bits(v[i].w * inv)) << 16);
    }
    uint4* dst = (uint4*)((char*)ws + WS_CB_OFF + (size_t)idx * 128);
    #pragma unroll
    for (int i = 0; i < 8; ++i)
        dst[i] = make_uint4(dw[4*i], dw[4*i+1], dw[4*i+2], dw[4*i+3]);
}

// ---------------------------------------------------------------- main ----
__global__ __launch_bounds__(TPB, 4) void rpq_main(
    const float* __restrict__ mel,
    const float* __restrict__ proj,
    const float* __restrict__ cb,
    const float* __restrict__ ws,
    int* __restrict__ out)
{
    const int tid  = threadIdx.x;
    const int b    = blockIdx.y;
    const int c    = blockIdx.z;
    const int t0   = blockIdx.x * TM;

    const int l    = tid & 63;
    const int wid  = tid >> 6;      // wave 0..3
    const int lrow = l & 15;        // A/B row-col within 16x16
    const int lgrp = l >> 4;        // k-octet group 0..3

    // projS: phase-1 only. cbuf/PL written strictly after S2.
    // cand/scv/sck alias cbuf — written strictly after the filter's final
    // barrier (cbuf dead), PL stays live through rescore.
    __shared__ union __align__(16) {
        float projS[NMELS * DDIM];              // 20480 B
        struct {
            union {
                char cbuf[2][KT * 128];         // 16384 B (bf16 dbuf, swizzled)
                struct {
                    uint32_t cand[TM][17][2];   // 8704 B
                    float    scv[TM][8];        // 2048 B
                    int      sck[TM][8];        // 2048 B
                } m;
            } a;
            float PL[TM * PPAD];                // 16896 B
        } p2;
    } U;                                        // total 33280 B

    const char*  wscb   = (const char*)ws + WS_CB_OFF + (size_t)c * (KCB * 128);
    const float* invn_g = ws + (size_t)c * KCB;

    // ---- stage proj[c] into LDS ----
    {
        const float4* src = (const float4*)(proj + (size_t)c * NMELS * DDIM);
        float4* dst = (float4*)U.projS;
        for (int i = tid; i < NMELS * DDIM / 4; i += TPB) dst[i] = src[i];
    }
    __syncthreads();                                  // S1

    // ---- issue tile-0 staging loads early ----
    const int srow = tid >> 2;     // staging row 0..63
    const int sq   = tid & 3;      // 32-byte quarter
    uint4 g0, g1;
    {
        const uint4* gp = (const uint4*)(wscb + (size_t)srow * 128 + sq * 32);
        g0 = gp[0]; g1 = gp[1];
    }

    // ---- phase 1: P[t][d]; thread = (tq = tid&15 -> 4 t's, dg = tid>>4 -> 4 d's)
    {
        const int tq = tid & 15;
        const int dg = tid >> 4;
        const int tbase  = t0 + tq * 4;
        const int tb_c   = (tbase <= TSTEPS - 4) ? tbase : (TSTEPS - 4); // clamp
        const float* mp  = mel + (size_t)b * NMELS * TSTEPS + tb_c;

        float Pa[4][4];
        #pragma unroll
        for (int i = 0; i < 4; ++i)
            #pragma unroll
            for (int j = 0; j < 4; ++j) Pa[i][j] = 0.f;

        for (int n = 0; n < NMELS; ++n) {
            const float4 m4 = *(const float4*)(mp + (size_t)n * TSTEPS);
            const float4 w  = *(const float4*)&U.projS[n * DDIM + dg * 4];
            Pa[0][0] = fmaf(m4.x, w.x, Pa[0][0]); Pa[0][1] = fmaf(m4.x, w.y, Pa[0][1]);
            Pa[0][2] = fmaf(m4.x, w.z, Pa[0][2]); Pa[0][3] = fmaf(m4.x, w.w, Pa[0][3]);
            Pa[1][0] = fmaf(m4.y, w.x, Pa[1][0]); Pa[1][1] = fmaf(m4.y, w.y, Pa[1][1]);
            Pa[1][2] = fmaf(m4.y, w.z, Pa[1][2]); Pa[1][3] = fmaf(m4.y, w.w, Pa[1][3]);
            Pa[2][0] = fmaf(m4.z, w.x, Pa[2][0]); Pa[2][1] = fmaf(m4.z, w.y, Pa[2][1]);
            Pa[2][2] = fmaf(m4.z, w.z, Pa[2][2]); Pa[2][3] = fmaf(m4.z, w.w, Pa[2][3]);
            Pa[3][0] = fmaf(m4.w, w.x, Pa[3][0]); Pa[3][1] = fmaf(m4.w, w.y, Pa[3][1]);
            Pa[3][2] = fmaf(m4.w, w.z, Pa[3][2]); Pa[3][3] = fmaf(m4.w, w.w, Pa[3][3]);
        }
        __syncthreads();                              // S2: projS reads done

        #pragma unroll
        for (int i = 0; i < 4; ++i)
            *(float4*)&U.p2.PL[(tq * 4 + i) * PPAD + dg * 4] =
                make_float4(Pa[i][0], Pa[i][1], Pa[i][2], Pa[i][3]);
    }

    // ---- write tile 0 (XOR-swizzled rows, R5/R6-proven addressing) ----
    {
        const int xw = (srow & 7) << 4;
        char* base = &U.p2.a.cbuf[0][srow * 128];
        *(uint4*)(base + ((sq * 32)      ^ xw)) = g0;
        *(uint4*)(base + ((sq * 32 + 16) ^ xw)) = g1;
    }
    __syncthreads();                                  // S3: PL + tile0 ready

    // ---- A fragments (bf16 RNE) from PL ----
    bf16x8 A0, A1;
    {
        const float* pr = &U.p2.PL[((wid << 4) + lrow) * PPAD];
        #pragma unroll
        for (int i = 0; i < 8; ++i) {
            A0[i] = (short)rne16(bits(pr[lgrp * 8 + i]));        // d 0..31
            A1[i] = (short)rne16(bits(pr[32 + lgrp * 8 + i]));   // d 32..63
        }
    }

    // ---- filter loop over 16 tiles (pre-normalized sims) ----
    float m1[4], m2[4];
    #pragma unroll
    for (int r = 0; r < 4; ++r) { m1[r] = -INFINITY; m2[r] = -INFINITY; }
    uint32_t idxv = (uint32_t)(1023 - lrow);  // payload = 1023 - k

    const int xr  = (lrow & 7) << 4;
    const int bo0 = (lgrp * 16) ^ xr;
    const int bo1 = (64 + lgrp * 16) ^ xr;

    for (int kt = 0; kt < NKT; ++kt) {
        const int cur = kt & 1;
        if (kt + 1 < NKT) {   // issue next-tile staging loads
            const uint4* gp = (const uint4*)(wscb + (size_t)(kt + 1) * (KT * 128)
                                             + (size_t)srow * 128 + sq * 32);
            g0 = gp[0]; g1 = gp[1];
        }
        const char* buf = U.p2.a.cbuf[cur];
        #pragma unroll
        for (int s = 0; s < 4; ++s) {
            const char* rowp = buf + (s * 16 + lrow) * 128;
            bf16x8 B0 = *(const bf16x8*)(rowp + bo0);
            bf16x8 B1 = *(const bf16x8*)(rowp + bo1);
            f32x4 acc = {0.f, 0.f, 0.f, 0.f};
            acc = __builtin_amdgcn_mfma_f32_16x16x32_bf16(A0, B0, acc, 0, 0, 0);
            acc = __builtin_amdgcn_mfma_f32_16x16x32_bf16(A1, B1, acc, 0, 0, 0);
            #pragma unroll
            for (int r = 0; r < 4; ++r) {
                const float pf = fbits((bits(acc[r]) & 0xFFFFFC00u) | idxv);
                m2[r] = __builtin_amdgcn_fmed3f(pf, m1[r], m2[r]);
                m1[r] = fmaxf(pf, m1[r]);
            }
            idxv -= 16u;
        }
        if (kt + 1 < NKT) {
            const int xw = (srow & 7) << 4;
            char* base = &U.p2.a.cbuf[cur ^ 1][srow * 128];
            *(uint4*)(base + ((sq * 32)      ^ xw)) = g0;
            *(uint4*)(base + ((sq * 32 + 16) ^ xw)) = g1;
        }
        __syncthreads();
    }
    // cbuf is dead from here (final loop barrier passed) -> cand may alias it.

    // ---- per-lane top-2 -> cand; C row t = wid*16 + lgrp*4 + r (m89) ----
    #pragma unroll
    for (int r = 0; r < 4; ++r) {
        const int trow = (wid << 4) + (lgrp << 2) + r;
        U.p2.a.m.cand[trow][lrow][0] = bits(m1[r]);
        U.p2.a.m.cand[trow][lrow][1] = bits(m2[r]);
    }
    __syncthreads();                                  // S4

    // ---- merge top-8 per t (4 threads/t redundantly), rescore 2 each ----
    {
        const int t = tid & 63;
        const int j = wid;
        float c1 = -INFINITY, c2 = -INFINITY, c3 = -INFINITY, c4 = -INFINITY;
        float c5 = -INFINITY, c6 = -INFINITY, c7 = -INFINITY, c8 = -INFINITY;
        for (int i = 0; i < 16; ++i) {
            #pragma unroll
            for (int jj = 0; jj < 2; ++jj) {
                const float p = fbits(U.p2.a.m.cand[t][i][jj]);
                c8 = fmaxf(fminf(p, c7), c8);
                c7 = fmaxf(fminf(p, c6), c7);
                c6 = fmaxf(fminf(p, c5), c6);
                c5 = fmaxf(fminf(p, c4), c5);
                c4 = fmaxf(fminf(p, c3), c4);
                c3 = fmaxf(fminf(p, c2), c3);
                c2 = fmaxf(fminf(p, c1), c2);
                c1 = fmaxf(p, c1);
            }
        }
        const float sel0 = (j == 0) ? c1 : (j == 1) ? c3 : (j == 2) ? c5 : c7;
        const float sel1 = (j == 0) ? c2 : (j == 1) ? c4 : (j == 2) ? c6 : c8;
        const float* pr  = &U.p2.PL[t * PPAD];
        const float* cbc = cb + (size_t)c * KCB * DDIM;
        #pragma unroll
        for (int e = 0; e < 2; ++e) {
            const float sel = e ? sel1 : sel0;
            const int kj = 1023 - (int)(bits(sel) & 0x3FFu);
            const float* cbr = cbc + (size_t)kj * DDIM;
            float a0 = 0.f, a1 = 0.f, a2 = 0.f, a3 = 0.f;
            #pragma unroll
            for (int i = 0; i < 16; ++i) {
                float4 pv = *(const float4*)(pr + i * 4);
                float4 cv = *(const float4*)(cbr + i * 4);
                a0 = fmaf(pv.x, cv.x, a0); a1 = fmaf(pv.y, cv.y, a1);
                a2 = fmaf(pv.z, cv.z, a2); a3 = fmaf(pv.w, cv.w, a3);
            }
            U.p2.a.m.scv[t][2*j + e] = ((a0 + a1) + (a2 + a3)) * invn_g[kj];
            U.p2.a.m.sck[t][2*j + e] = kj;
        }
    }
    __syncthreads();                                  // S5

    if (tid < TM) {
        const int tg = t0 + tid;
        if (tg < TSTEPS) {
            float best = U.p2.a.m.scv[tid][0];
            int   bk   = U.p2.a.m.sck[tid][0];
            #pragma unroll
            for (int s2 = 1; s2 < 8; ++s2) {
                const float v = U.p2.a.m.scv[tid][s2];
                const int  kk = U.p2.a.m.sck[tid][s2];
                if (v > best || (v == best && kk < bk)) { best = v; bk = kk; }
            }
            out[((size_t)c * B + b) * TSTEPS + tg] = bk;
        }
    }
}

// ------------------------------------------------------------- fallback ----
__global__ __launch_bounds__(TPB, 2) void rpq_fallback(
    const float* __restrict__ mel, const float* __restrict__ proj,
    const float* __restrict__ cb, int* __restrict__ out)
{
    const int tid = threadIdx.x;
    const int b = blockIdx.y, c = blockIdx.z;
    const int t0 = blockIdx.x * (TPB * 2) + tid;
    const int t1 = t0 + TPB;
    const int tc0 = (t0 < TSTEPS) ? t0 : (TSTEPS - 1);
    const int tc1 = (t1 < TSTEPS) ? t1 : (TSTEPS - 1);

    __shared__ union { float projS[NMELS*DDIM]; float cbS[2][64*DDIM]; } sh;
    __shared__ float invn[KCB];
    const float* cbc = cb + (size_t)c * KCB * DDIM;
    {
        const float4* src = (const float4*)(proj + (size_t)c * NMELS * DDIM);
        float4* dst = (float4*)sh.projS;
        for (int i = tid; i < NMELS*DDIM/4; i += TPB) dst[i] = src[i];
    }
    for (int j = 0; j < KCB/TPB; ++j) {
        const int k = j*TPB + tid;
        const float4* r = (const float4*)(cbc + (size_t)k * DDIM);
        float s = 0.f;
        #pragma unroll
        for (int i = 0; i < DDIM/4; ++i) {
            float4 v = r[i]; s += v.x*v.x + v.y*v.y + v.z*v.z + v.w*v.w;
        }
        invn[k] = 1.0f / fmaxf(sqrtf(s), 1e-12f);
    }
    float4 r0, r1, r2, r3;
    { const float4* g = (const float4*)cbc;
      r0 = g[tid]; r1 = g[tid+256]; r2 = g[tid+512]; r3 = g[tid+768]; }
    __syncthreads();
    float P0[DDIM], P1[DDIM];
    #pragma unroll
    for (int d = 0; d < DDIM; ++d) { P0[d] = 0.f; P1[d] = 0.f; }
    const float* mp = mel + (size_t)b * NMELS * TSTEPS;
    for (int n = 0; n < NMELS; ++n) {
        const float m0 = mp[(size_t)n*TSTEPS + tc0];
        const float m1_ = mp[(size_t)n*TSTEPS + tc1];
        const float4* ps = (const float4*)(sh.projS + n*DDIM);
        #pragma unroll
        for (int i = 0; i < DDIM/4; ++i) {
            float4 v = ps[i];
            P0[4*i+0]=fmaf(m0,v.x,P0[4*i+0]); P0[4*i+1]=fmaf(m0,v.y,P0[4*i+1]);
            P0[4*i+2]=fmaf(m0,v.z,P0[4*i+2]); P0[4*i+3]=fmaf(m0,v.w,P0[4*i+3]);
            P1[4*i+0]=fmaf(m1_,v.x,P1[4*i+0]); P1[4*i+1]=fmaf(m1_,v.y,P1[4*i+1]);
            P1[4*i+2]=fmaf(m1_,v.z,P1[4*i+2]); P1[4*i+3]=fmaf(m1_,v.w,P1[4*i+3]);
        }
    }
    __syncthreads();
    { float4* dst = (float4*)sh.cbS[0];
      dst[tid]=r0; dst[tid+256]=r1; dst[tid+512]=r2; dst[tid+768]=r3; }
    { const float4* g = (const float4*)(cbc + (size_t)64*DDIM);
      r0=g[tid]; r1=g[tid+256]; r2=g[tid+512]; r3=g[tid+768]; }
    __syncthreads();
    float best0 = -INFINITY, best1 = -INFINITY; int bi0 = 0, bi1 = 0;
    for (int kt = 0; kt < KCB/64; ++kt) {
        const int cur = kt & 1;
        const float* base = sh.cbS[cur];
        const int kbase = kt * 64;
        #pragma unroll 2
        for (int kk = 0; kk < 64; ++kk) {
            const float4* row = (const float4*)(base + kk*DDIM);
            float a0=0,a1=0,a2=0,a3=0,b0=0,b1=0,b2=0,b3=0;
            #pragma unroll
            for (int i = 0; i < DDIM/4; ++i) {
                float4 v = row[i];
                a0=fmaf(P0[4*i+0],v.x,a0); a1=fmaf(P0[4*i+1],v.y,a1);
                a2=fmaf(P0[4*i+2],v.z,a2); a3=fmaf(P0[4*i+3],v.w,a3);
                b0=fmaf(P1[4*i+0],v.x,b0); b1=fmaf(P1[4*i+1],v.y,b1);
                b2=fmaf(P1[4*i+2],v.z,b2); b3=fmaf(P1[4*i+3],v.w,b3);
            }
            const int k = kbase + kk;
            const float w = invn[k];
            const float s0 = ((a0+a1)+(a2+a3))*w;
            const float s1 = ((b0+b1)+(b2+b3))*w;
            if (s0 > best0) { best0 = s0; bi0 = k; }
            if (s1 > best1) { best1 = s1; bi1 = k; }
        }
        if (kt + 1 < KCB/64) {
            float4* dst = (float4*)sh.cbS[cur ^ 1];
            dst[tid]=r0; dst[tid+256]=r1; dst[tid+512]=r2; dst[tid+768]=r3;
            if (kt + 2 < KCB/64) {
                const float4* g = (const float4*)(cbc + (size_t)(kt+2)*64*DDIM);
                r0=g[tid]; r1=g[tid+256]; r2=g[tid+512]; r3=g[tid+768];
            }
        }
        __syncthreads();
    }
    const size_t ob = ((size_t)c * B + b) * TSTEPS;
    if (t0 < TSTEPS) out[ob + t0] = bi0;
    if (t1 < TSTEPS) out[ob + t1] = bi1;
}

// --------------------------------------------------------------- launch ----
extern "C" void kernel_launch(void* const* d_in, const int* in_sizes, int n_in,
                              void* d_out, int out_size, void* d_ws, size_t ws_size,
                              hipStream_t stream) {
    const float* mel  = (const float*)d_in[0];
    const float* proj = (const float*)d_in[1];
    const float* cb   = (const float*)d_in[2];
    int* out = (int*)d_out;

    if (ws_size >= (size_t)WS_NEEDED) {   // proven true on this harness (R4)
        float* ws = (float*)d_ws;
        rpq_prep<<<dim3((NCB*KCB + TPB - 1)/TPB), dim3(TPB), 0, stream>>>(cb, ws);
        dim3 grid((TSTEPS + TM - 1) / TM, B, NCB);     // (63, 32, 2)
        rpq_main<<<grid, dim3(TPB), 0, stream>>>(mel, proj, cb, ws, out);
    } else {
        dim3 grid((TSTEPS + TPB*2 - 1) / (TPB*2), B, NCB);
        rpq_fallback<<<grid, dim3(TPB), 0, stream>>>(mel, proj, cb, out);
    }
}